// Round 1
// baseline (3125.495 us; speedup 1.0000x reference)
//
#include <hip/hip_runtime.h>
#include <math.h>

#define S_LEN 3072
#define DIM 1536
#define NHEADS 16
#define HDIM 96
#define NPAIR 48

#define BM 128
#define BN 128
#define BK 16

// ---------------- fp32 tiled GEMM: out = X[M,K] @ W[K,N] + bias ----------------
// QKV=true: grid.z selects (W0,B0)/(W1,B1)/(W2,B2), epilogue writes [z][head][s][hd]
// QKV=false: plain row-major [m][n] into out.
template<bool QKV>
__global__ __launch_bounds__(256)
void gemm128(const float* __restrict__ X,
             const float* __restrict__ W0, const float* __restrict__ W1, const float* __restrict__ W2,
             const float* __restrict__ B0, const float* __restrict__ B1, const float* __restrict__ B2,
             float* __restrict__ out)
{
    const int tid = threadIdx.x;
    const int bx = blockIdx.x, by = blockIdx.y, bz = blockIdx.z;
    const float* W = W0; const float* bias = B0;
    if (QKV) { if (bz == 1) { W = W1; bias = B1; } else if (bz == 2) { W = W2; bias = B2; } }

    __shared__ float As[BK][BM];        // [k][m] (transposed on store)
    __shared__ float Bs[BK][BN + 4];    // +4 pad keeps float4 alignment

    const int m0 = by * BM, n0 = bx * BN;
    const int tx = tid & 15, ty = tid >> 4;

    float acc[8][8];
#pragma unroll
    for (int i = 0; i < 8; i++)
#pragma unroll
        for (int j = 0; j < 8; j++) acc[i][j] = 0.f;

    for (int k0 = 0; k0 < DIM; k0 += BK) {
        // A tile: 128 rows x 16 cols, 512 float4 loads
#pragma unroll
        for (int i = tid; i < 512; i += 256) {
            int row = i >> 2, c4 = (i & 3) << 2;
            float4 a4 = *(const float4*)&X[(size_t)(m0 + row) * DIM + k0 + c4];
            As[c4 + 0][row] = a4.x; As[c4 + 1][row] = a4.y;
            As[c4 + 2][row] = a4.z; As[c4 + 3][row] = a4.w;
        }
        // B tile: 16 rows x 128 cols
#pragma unroll
        for (int i = tid; i < 512; i += 256) {
            int row = i >> 5, c4 = (i & 31) << 2;
            *(float4*)&Bs[row][c4] = *(const float4*)&W[(size_t)(k0 + row) * DIM + n0 + c4];
        }
        __syncthreads();
#pragma unroll
        for (int kk = 0; kk < BK; kk++) {
            float rm[8], rn[8];
            *(float4*)&rm[0] = *(const float4*)&As[kk][ty * 8];
            *(float4*)&rm[4] = *(const float4*)&As[kk][ty * 8 + 4];
            *(float4*)&rn[0] = *(const float4*)&Bs[kk][tx * 8];
            *(float4*)&rn[4] = *(const float4*)&Bs[kk][tx * 8 + 4];
#pragma unroll
            for (int i = 0; i < 8; i++)
#pragma unroll
                for (int j = 0; j < 8; j++)
                    acc[i][j] = fmaf(rm[i], rn[j], acc[i][j]);
        }
        __syncthreads();
    }

#pragma unroll
    for (int i = 0; i < 8; i++) {
        int m = m0 + ty * 8 + i;
#pragma unroll
        for (int j = 0; j < 8; j++) {
            int n = n0 + tx * 8 + j;
            float v = acc[i][j] + bias[n];
            if (QKV) {
                int head = n / HDIM, hd = n % HDIM;
                out[(((size_t)bz * NHEADS + head) * S_LEN + m) * HDIM + hd] = v;
            } else {
                out[(size_t)m * DIM + n] = v;
            }
        }
    }
}

// ---------------- RoPE: rotate channel pairs 16..47 of q and k in place ----------------
// layout: [head][s][hd]; pair jc in [16,32) rotated by h-position, [32,48) by w-position
__global__ __launch_bounds__(256)
void rope_kernel(float* __restrict__ qb, float* __restrict__ kb,
                 const float* __restrict__ fc, const float* __restrict__ fs)
{
    const int per_tensor = NHEADS * S_LEN * 32;
    int idx = blockIdx.x * 256 + threadIdx.x;
    if (idx >= 2 * per_tensor) return;
    float* buf = (idx < per_tensor) ? qb : kb;
    int r  = idx % per_tensor;
    int head = r / (S_LEN * 32);
    int r2 = r % (S_LEN * 32);
    int s  = r2 >> 5;
    int jc = 16 + (r2 & 31);
    int pos = (jc < 32) ? (s >> 6) : (s & 63);   // h-index = s/64, w-index = s%64
    float c  = fc[pos * NPAIR + jc];
    float sn = fs[pos * NPAIR + jc];
    size_t base = (((size_t)head * S_LEN) + s) * HDIM + 2 * jc;
    float2 xv = *(float2*)&buf[base];
    float yr = xv.x * c - xv.y * sn;
    float yi = xv.x * sn + xv.y * c;
    *(float2*)&buf[base] = make_float2(yr, yi);
}

// ---------------- flash-style attention, fp32, online softmax ----------------
// block = (head, 16 query rows); K/V tiles of 32 rows staged in LDS
__global__ __launch_bounds__(256)
void attn_kernel(const float* __restrict__ qb, const float* __restrict__ kb,
                 const float* __restrict__ vb, float* __restrict__ ao)
{
    const int t = threadIdx.x;
    const int h = blockIdx.y;
    const int sq0 = blockIdx.x * 16;

    __shared__ float qs[16][HDIM];
    __shared__ float Ks[32][HDIM + 1];   // stride 97 -> bank (j+d)%32, conflict-free
    __shared__ float Vs[32][HDIM];       // bank depends only on d -> broadcast-free
    __shared__ float st[16][33];         // stride 33 -> bank (r+j)%32
    __shared__ float mrow[16], lrow[16], arow[16];

    for (int i = t; i < 384; i += 256) {
        int row = i / 24, c4 = (i % 24) * 4;
        *(float4*)&qs[row][c4] =
            *(const float4*)&qb[(((size_t)h * S_LEN) + sq0 + row) * HDIM + c4];
    }
    if (t < 16) { mrow[t] = -INFINITY; lrow[t] = 0.f; }

    float o[6] = {0, 0, 0, 0, 0, 0};
    const int r = t & 15, g = t >> 4, d0 = g * 6;   // PV mapping: O[r][d0..d0+6)
    const int jsc = t & 31, rsc = t >> 5;           // score mapping: (rsc, jsc) & (rsc+8, jsc)
    const float scale_ = 0.10206207261596577f;      // 1/sqrt(96)

    for (int kt = 0; kt < S_LEN / 32; ++kt) {
        const int j0 = kt * 32;
        __syncthreads();   // prev PV done before K/V overwrite
        for (int i = t; i < 768; i += 256) {
            int row = i / 24, c4 = (i % 24) * 4;
            float4 k4 = *(const float4*)&kb[(((size_t)h * S_LEN) + j0 + row) * HDIM + c4];
            Ks[row][c4 + 0] = k4.x; Ks[row][c4 + 1] = k4.y;
            Ks[row][c4 + 2] = k4.z; Ks[row][c4 + 3] = k4.w;
            *(float4*)&Vs[row][c4] =
                *(const float4*)&vb[(((size_t)h * S_LEN) + j0 + row) * HDIM + c4];
        }
        __syncthreads();
        // scores: 512 dots of length 96; each thread does rows rsc and rsc+8, col jsc
        {
            float a0 = 0.f, a1 = 0.f;
#pragma unroll 8
            for (int d = 0; d < HDIM; ++d) {
                float kv = Ks[jsc][d];
                a0 = fmaf(qs[rsc][d],     kv, a0);
                a1 = fmaf(qs[rsc + 8][d], kv, a1);
            }
            st[rsc][jsc]     = a0 * scale_;
            st[rsc + 8][jsc] = a1 * scale_;
        }
        __syncthreads();
        // online softmax update: 8 lanes per row, shfl reduction
        if (t < 128) {
            int rr = t >> 3, q8 = t & 7;
            float mx = -INFINITY;
#pragma unroll
            for (int u = 0; u < 4; u++) mx = fmaxf(mx, st[rr][q8 * 4 + u]);
#pragma unroll
            for (int off = 1; off < 8; off <<= 1) mx = fmaxf(mx, __shfl_xor(mx, off));
            float mo = mrow[rr];
            float mn = fmaxf(mo, mx);
            float sum = 0.f;
#pragma unroll
            for (int u = 0; u < 4; u++) {
                float p = __expf(st[rr][q8 * 4 + u] - mn);
                st[rr][q8 * 4 + u] = p;
                sum += p;
            }
#pragma unroll
            for (int off = 1; off < 8; off <<= 1) sum += __shfl_xor(sum, off);
            if (q8 == 0) {
                float a = __expf(mo - mn);   // first tile: exp(-inf)=0
                arow[rr] = a;
                lrow[rr] = lrow[rr] * a + sum;
                mrow[rr] = mn;
            }
        }
        __syncthreads();
        // PV accumulate
        {
            float a = arow[r];
#pragma unroll
            for (int i = 0; i < 6; i++) o[i] *= a;
#pragma unroll 4
            for (int j = 0; j < 32; j++) {
                float p = st[r][j];
#pragma unroll
                for (int i = 0; i < 6; i++)
                    o[i] = fmaf(p, Vs[j][d0 + i], o[i]);
            }
        }
    }
    float invl = 1.f / lrow[r];
#pragma unroll
    for (int i = 0; i < 6; i++)
        ao[((size_t)(sq0 + r)) * DIM + h * HDIM + d0 + i] = o[i] * invl;
}

extern "C" void kernel_launch(void* const* d_in, const int* in_sizes, int n_in,
                              void* d_out, int out_size, void* d_ws, size_t ws_size,
                              hipStream_t stream) {
    const float* x  = (const float*)d_in[0];
    const float* wq = (const float*)d_in[1];
    const float* bq = (const float*)d_in[2];
    const float* wk = (const float*)d_in[3];
    const float* bk = (const float*)d_in[4];
    const float* wv = (const float*)d_in[5];
    const float* bv = (const float*)d_in[6];
    const float* wo = (const float*)d_in[7];
    const float* bo = (const float*)d_in[8];
    const float* fc = (const float*)d_in[9];
    const float* fs = (const float*)d_in[10];
    float* out = (float*)d_out;

    float* ws = (float*)d_ws;
    const size_t per = (size_t)NHEADS * S_LEN * HDIM;   // 4.72M floats
    float* qb = ws;             // [NH][S][HD]
    float* kb = qb + per;
    float* vb = kb + per;
    float* ao = vb + per;       // [S][DIM]

    // fused QKV projection (z selects weight) with [head][s][hd] epilogue
    gemm128<true><<<dim3(DIM / BN, S_LEN / BM, 3), 256, 0, stream>>>(
        x, wq, wk, wv, bq, bk, bv, qb);
    // RoPE on q and k (channels 16..47)
    rope_kernel<<<(2 * NHEADS * S_LEN * 32) / 256, 256, 0, stream>>>(qb, kb, fc, fs);
    // attention
    attn_kernel<<<dim3(S_LEN / 16, NHEADS), 256, 0, stream>>>(qb, kb, vb, ao);
    // output projection -> d_out
    gemm128<false><<<dim3(DIM / BN, S_LEN / BM, 1), 256, 0, stream>>>(
        ao, wo, nullptr, nullptr, bo, nullptr, nullptr, out);
}

// Round 2
// 1528.249 us; speedup vs baseline: 2.0451x; 2.0451x over previous
//
#include <hip/hip_runtime.h>
#include <math.h>

#define S_LEN 3072
#define DIM 1536
#define NHEADS 16
#define HDIM 96
#define NPAIR 48

#define BM 128
#define BN 128
#define BK 16

typedef __attribute__((ext_vector_type(8))) short short8;
typedef __attribute__((ext_vector_type(4))) float f32x4;

__device__ inline unsigned short f2bf(float f) {
    unsigned int u = __float_as_uint(f);
    unsigned int r = (u + 0x7FFFu + ((u >> 16) & 1u)) >> 16;
    return (unsigned short)r;
}
__device__ inline unsigned int packbf2(float a, float b) {
    return (unsigned int)f2bf(a) | ((unsigned int)f2bf(b) << 16);
}

// ---------------- fp32 tiled GEMM: out = X[M,K] @ W[K,N] + bias ----------------
template<bool QKV>
__global__ __launch_bounds__(256)
void gemm128(const float* __restrict__ X,
             const float* __restrict__ W0, const float* __restrict__ W1, const float* __restrict__ W2,
             const float* __restrict__ B0, const float* __restrict__ B1, const float* __restrict__ B2,
             float* __restrict__ out)
{
    const int tid = threadIdx.x;
    const int bx = blockIdx.x, by = blockIdx.y, bz = blockIdx.z;
    const float* W = W0; const float* bias = B0;
    if (QKV) { if (bz == 1) { W = W1; bias = B1; } else if (bz == 2) { W = W2; bias = B2; } }

    __shared__ float As[BK][BM];
    __shared__ float Bs[BK][BN + 4];

    const int m0 = by * BM, n0 = bx * BN;
    const int tx = tid & 15, ty = tid >> 4;

    float acc[8][8];
#pragma unroll
    for (int i = 0; i < 8; i++)
#pragma unroll
        for (int j = 0; j < 8; j++) acc[i][j] = 0.f;

    for (int k0 = 0; k0 < DIM; k0 += BK) {
#pragma unroll
        for (int i = tid; i < 512; i += 256) {
            int row = i >> 2, c4 = (i & 3) << 2;
            float4 a4 = *(const float4*)&X[(size_t)(m0 + row) * DIM + k0 + c4];
            As[c4 + 0][row] = a4.x; As[c4 + 1][row] = a4.y;
            As[c4 + 2][row] = a4.z; As[c4 + 3][row] = a4.w;
        }
#pragma unroll
        for (int i = tid; i < 512; i += 256) {
            int row = i >> 5, c4 = (i & 31) << 2;
            *(float4*)&Bs[row][c4] = *(const float4*)&W[(size_t)(k0 + row) * DIM + n0 + c4];
        }
        __syncthreads();
#pragma unroll
        for (int kk = 0; kk < BK; kk++) {
            float rm[8], rn[8];
            *(float4*)&rm[0] = *(const float4*)&As[kk][ty * 8];
            *(float4*)&rm[4] = *(const float4*)&As[kk][ty * 8 + 4];
            *(float4*)&rn[0] = *(const float4*)&Bs[kk][tx * 8];
            *(float4*)&rn[4] = *(const float4*)&Bs[kk][tx * 8 + 4];
#pragma unroll
            for (int i = 0; i < 8; i++)
#pragma unroll
                for (int j = 0; j < 8; j++)
                    acc[i][j] = fmaf(rm[i], rn[j], acc[i][j]);
        }
        __syncthreads();
    }

#pragma unroll
    for (int i = 0; i < 8; i++) {
        int m = m0 + ty * 8 + i;
#pragma unroll
        for (int j = 0; j < 8; j++) {
            int n = n0 + tx * 8 + j;
            float v = acc[i][j] + bias[n];
            if (QKV) {
                int head = n / HDIM, hd = n % HDIM;
                out[(((size_t)bz * NHEADS + head) * S_LEN + m) * HDIM + hd] = v;
            } else {
                out[(size_t)m * DIM + n] = v;
            }
        }
    }
}

// ---------------- RoPE (unchanged, fp32 in-place on qb/kb) ----------------
__global__ __launch_bounds__(256)
void rope_kernel(float* __restrict__ qb, float* __restrict__ kb,
                 const float* __restrict__ fc, const float* __restrict__ fs)
{
    const int per_tensor = NHEADS * S_LEN * 32;
    int idx = blockIdx.x * 256 + threadIdx.x;
    if (idx >= 2 * per_tensor) return;
    float* buf = (idx < per_tensor) ? qb : kb;
    int r  = idx % per_tensor;
    int head = r / (S_LEN * 32);
    int r2 = r % (S_LEN * 32);
    int s  = r2 >> 5;
    int jc = 16 + (r2 & 31);
    int pos = (jc < 32) ? (s >> 6) : (s & 63);
    float c  = fc[pos * NPAIR + jc];
    float sn = fs[pos * NPAIR + jc];
    size_t base = (((size_t)head * S_LEN) + s) * HDIM + 2 * jc;
    float2 xv = *(float2*)&buf[base];
    float yr = xv.x * c - xv.y * sn;
    float yi = xv.x * sn + xv.y * c;
    *(float2*)&buf[base] = make_float2(yr, yi);
}

// ---------------- MFMA bf16 flash attention ----------------
// block = (head, 64 q rows), 4 waves x 16 rows. K-tile = 64 keys.
// Q (pre-scaled) in registers as A-frags; K in LDS [key][d] (bf16, stride 104);
// V in LDS transposed [d][key] (stride 72); P wave-private LDS [row][key] (stride 72).
__global__ __launch_bounds__(256)
void attn_mfma_kernel(const float* __restrict__ qb, const float* __restrict__ kb,
                      const float* __restrict__ vb, float* __restrict__ ao)
{
    __shared__ __align__(16) unsigned short Ks[64][104];   // 13312 B
    __shared__ __align__(16) unsigned short Vt[96][72];    // 13824 B
    __shared__ __align__(16) unsigned short Ps[4][16][72]; //  9216 B

    const int tid  = threadIdx.x;
    const int wid  = tid >> 6;
    const int lane = tid & 63;
    const int ln   = lane & 15;
    const int quad = lane >> 4;
    const int h    = blockIdx.y;
    const int q0   = blockIdx.x * 64;
    const float scale_ = 0.10206207261596577f;  // 1/sqrt(96)

    // Q A-frags: row = q0 + wid*16 + ln, k-chunk = kb*32 + quad*8 (3 frags of 8 bf16)
    short8 aq[3];
    {
        const float* qrow = qb + (((size_t)h * S_LEN) + q0 + wid * 16 + ln) * HDIM;
#pragma unroll
        for (int kb3 = 0; kb3 < 3; kb3++) {
            int d0 = kb3 * 32 + quad * 8;
            float4 a = *(const float4*)&qrow[d0];
            float4 b = *(const float4*)&qrow[d0 + 4];
            short8 v;
            v[0] = (short)f2bf(a.x * scale_); v[1] = (short)f2bf(a.y * scale_);
            v[2] = (short)f2bf(a.z * scale_); v[3] = (short)f2bf(a.w * scale_);
            v[4] = (short)f2bf(b.x * scale_); v[5] = (short)f2bf(b.y * scale_);
            v[6] = (short)f2bf(b.z * scale_); v[7] = (short)f2bf(b.w * scale_);
            aq[kb3] = v;
        }
    }

    f32x4 o[6];
#pragma unroll
    for (int dn = 0; dn < 6; dn++) o[dn] = (f32x4){0.f, 0.f, 0.f, 0.f};
    float m_[4] = {-INFINITY, -INFINITY, -INFINITY, -INFINITY};
    float l_[4] = {0.f, 0.f, 0.f, 0.f};

    const float* kbase = kb + ((size_t)h * S_LEN) * HDIM;
    const float* vbase = vb + ((size_t)h * S_LEN) * HDIM;

    for (int kt = 0; kt < S_LEN / 64; ++kt) {
        const int j0 = kt * 64;
        __syncthreads();   // previous tile's Ks/Vt reads complete
        // stage K: 64x96 fp32 -> bf16 [key][d]
        for (int i = tid; i < 1536; i += 256) {
            int row = i / 24, c4 = (i % 24) * 4;
            float4 k4 = *(const float4*)&kbase[(size_t)(j0 + row) * HDIM + c4];
            ushort4 w;
            w.x = f2bf(k4.x); w.y = f2bf(k4.y); w.z = f2bf(k4.z); w.w = f2bf(k4.w);
            *(ushort4*)&Ks[row][c4] = w;
        }
        // stage V transposed: [d][key] bf16, packed pairs
        for (int i = tid; i < 3072; i += 256) {
            int kp = i & 31, d = i >> 5;
            float a = vbase[(size_t)(j0 + 2 * kp) * HDIM + d];
            float b = vbase[(size_t)(j0 + 2 * kp + 1) * HDIM + d];
            *(unsigned int*)&Vt[d][2 * kp] = packbf2(a, b);
        }
        __syncthreads();

        // QK^T: scores 16x64 per wave (D-layout: key = nb*16+ln, row = quad*4+reg)
        f32x4 s[4];
#pragma unroll
        for (int nb = 0; nb < 4; nb++) {
            f32x4 acc = (f32x4){0.f, 0.f, 0.f, 0.f};
#pragma unroll
            for (int kb3 = 0; kb3 < 3; kb3++) {
                short8 bk = *(const short8*)&Ks[nb * 16 + ln][kb3 * 32 + quad * 8];
                acc = __builtin_amdgcn_mfma_f32_16x16x32_bf16(aq[kb3], bk, acc, 0, 0, 0);
            }
            s[nb] = acc;
        }

        // online softmax (per wave; row r -> reg r, 16 lanes of this quad share row)
        float mx[4], al[4];
#pragma unroll
        for (int r = 0; r < 4; r++)
            mx[r] = fmaxf(fmaxf(s[0][r], s[1][r]), fmaxf(s[2][r], s[3][r]));
#pragma unroll
        for (int msk = 1; msk < 16; msk <<= 1)
#pragma unroll
            for (int r = 0; r < 4; r++) mx[r] = fmaxf(mx[r], __shfl_xor(mx[r], msk));
#pragma unroll
        for (int r = 0; r < 4; r++) {
            float mn = fmaxf(m_[r], mx[r]);
            al[r] = __expf(m_[r] - mn);
            m_[r] = mn;
        }
        float rs[4] = {0.f, 0.f, 0.f, 0.f};
#pragma unroll
        for (int nb = 0; nb < 4; nb++)
#pragma unroll
            for (int r = 0; r < 4; r++) {
                float p = __expf(s[nb][r] - m_[r]);
                s[nb][r] = p;
                rs[r] += p;
            }
#pragma unroll
        for (int msk = 1; msk < 16; msk <<= 1)
#pragma unroll
            for (int r = 0; r < 4; r++) rs[r] += __shfl_xor(rs[r], msk);
#pragma unroll
        for (int r = 0; r < 4; r++) l_[r] = l_[r] * al[r] + rs[r];

        // write P (bf16) to wave-private LDS in A-layout [row][key], pair-packed b32
        {
            int rsel = (lane & 1) ? 2 : 0;
#pragma unroll
            for (int nb = 0; nb < 4; nb++) {
                int key = nb * 16 + ln;
                float pq[4];
#pragma unroll
                for (int r = 0; r < 4; r++) pq[r] = __shfl_xor(s[nb][r], 1);
                unsigned int w[4];
#pragma unroll
                for (int r = 0; r < 4; r++)
                    w[r] = (lane & 1) ? packbf2(pq[r], s[nb][r]) : packbf2(s[nb][r], pq[r]);
                int rbase = quad * 4 + rsel;
                *(unsigned int*)&Ps[wid][rbase][key & ~1]     = w[rsel];
                *(unsigned int*)&Ps[wid][rbase + 1][key & ~1] = w[rsel + 1];
            }
        }

        // rescale O accumulator
#pragma unroll
        for (int dn = 0; dn < 6; dn++)
#pragma unroll
            for (int r = 0; r < 4; r++) o[dn][r] *= al[r];

        // PV: A = P (wave-private), B = Vt
        short8 ap[2];
#pragma unroll
        for (int kb2 = 0; kb2 < 2; kb2++)
            ap[kb2] = *(const short8*)&Ps[wid][ln][kb2 * 32 + quad * 8];
#pragma unroll
        for (int dn = 0; dn < 6; dn++) {
#pragma unroll
            for (int kb2 = 0; kb2 < 2; kb2++) {
                short8 bv = *(const short8*)&Vt[dn * 16 + ln][kb2 * 32 + quad * 8];
                o[dn] = __builtin_amdgcn_mfma_f32_16x16x32_bf16(ap[kb2], bv, o[dn], 0, 0, 0);
            }
        }
    }

    float inv[4];
#pragma unroll
    for (int r = 0; r < 4; r++) inv[r] = 1.f / l_[r];
#pragma unroll
    for (int dn = 0; dn < 6; dn++)
#pragma unroll
        for (int r = 0; r < 4; r++) {
            int row = q0 + wid * 16 + quad * 4 + r;
            ao[(size_t)row * DIM + h * HDIM + dn * 16 + ln] = o[dn][r] * inv[r];
        }
}

extern "C" void kernel_launch(void* const* d_in, const int* in_sizes, int n_in,
                              void* d_out, int out_size, void* d_ws, size_t ws_size,
                              hipStream_t stream) {
    const float* x  = (const float*)d_in[0];
    const float* wq = (const float*)d_in[1];
    const float* bq = (const float*)d_in[2];
    const float* wk = (const float*)d_in[3];
    const float* bk = (const float*)d_in[4];
    const float* wv = (const float*)d_in[5];
    const float* bv = (const float*)d_in[6];
    const float* wo = (const float*)d_in[7];
    const float* bo = (const float*)d_in[8];
    const float* fc = (const float*)d_in[9];
    const float* fs = (const float*)d_in[10];
    float* out = (float*)d_out;

    float* ws = (float*)d_ws;
    const size_t per = (size_t)NHEADS * S_LEN * HDIM;
    float* qb = ws;
    float* kb = qb + per;
    float* vb = kb + per;
    float* ao = vb + per;

    gemm128<true><<<dim3(DIM / BN, S_LEN / BM, 3), 256, 0, stream>>>(
        x, wq, wk, wv, bq, bk, bv, qb);
    rope_kernel<<<(2 * NHEADS * S_LEN * 32) / 256, 256, 0, stream>>>(qb, kb, fc, fs);
    attn_mfma_kernel<<<dim3(S_LEN / 64, NHEADS), 256, 0, stream>>>(qb, kb, vb, ao);
    gemm128<false><<<dim3(DIM / BN, S_LEN / BM, 1), 256, 0, stream>>>(
        ao, wo, nullptr, nullptr, bo, nullptr, nullptr, out);
}

// Round 4
// 619.716 us; speedup vs baseline: 5.0434x; 2.4660x over previous
//
#include <hip/hip_runtime.h>
#include <math.h>

#define S_LEN 3072
#define DIM 1536
#define NHEADS 16
#define HDIM 96
#define NPAIR 48

typedef __attribute__((ext_vector_type(8))) _Float16 half8;
typedef __attribute__((ext_vector_type(4))) _Float16 half4v;
typedef __attribute__((ext_vector_type(2))) _Float16 half2v;
typedef __attribute__((ext_vector_type(4))) float f32x4;

__device__ inline void gload16(const void* g, void* l) {
    __builtin_amdgcn_global_load_lds(
        (const __attribute__((address_space(1))) void*)g,
        (__attribute__((address_space(3))) void*)l, 16, 0, 0);
}

__device__ inline unsigned int packh2(float a, float b) {
    _Float16 ha = (_Float16)a, hb = (_Float16)b;
    unsigned short ua = *(unsigned short*)&ha;
    unsigned short ub = *(unsigned short*)&hb;
    return (unsigned int)ua | ((unsigned int)ub << 16);
}

// ---------------- prep: fp32 -> fp16 elementwise ----------------
__global__ __launch_bounds__(256)
void convert_f32_f16(const float* __restrict__ src, _Float16* __restrict__ dst, int n4)
{
    int i = blockIdx.x * 256 + threadIdx.x;
    if (i < n4) {
        float4 v = *(const float4*)&src[(size_t)i * 4];
        half4v h = { (_Float16)v.x, (_Float16)v.y, (_Float16)v.z, (_Float16)v.w };
        *(half4v*)&dst[(size_t)i * 4] = h;
    }
}

// ---------------- prep: W[k][n] fp32 -> Wt[n][k] fp16 (64x64 LDS tiles) ----------------
__global__ __launch_bounds__(256)
void transpose_w(const float* __restrict__ w0, const float* __restrict__ w1,
                 const float* __restrict__ w2, const float* __restrict__ w3,
                 _Float16* __restrict__ wt)
{
    __shared__ _Float16 t[64][68];
    const int z = blockIdx.z;
    const float* W = (z == 0) ? w0 : (z == 1) ? w1 : (z == 2) ? w2 : w3;
    _Float16* O = wt + (size_t)z * DIM * DIM;
    const int k0 = blockIdx.y * 64, n0 = blockIdx.x * 64;
    const int tid = threadIdx.x;
    const int r = tid >> 4, c4 = (tid & 15) * 4;
#pragma unroll
    for (int g = 0; g < 4; g++) {
        int kk = r + g * 16;
        float4 v = *(const float4*)&W[(size_t)(k0 + kk) * DIM + n0 + c4];
        t[c4 + 0][kk] = (_Float16)v.x; t[c4 + 1][kk] = (_Float16)v.y;
        t[c4 + 2][kk] = (_Float16)v.z; t[c4 + 3][kk] = (_Float16)v.w;
    }
    __syncthreads();
    const int nr = tid >> 2, ks = (tid & 3) * 16;
#pragma unroll
    for (int s = 0; s < 4; s++)
        *(ushort4*)&O[(size_t)(n0 + nr) * DIM + k0 + ks + s * 4] =
            *(ushort4*)&t[nr][ks + s * 4];
}

// ---------------- fp16 MFMA GEMM: out = Xh[M,K] @ Wt^T + bias ----------------
// Xh fp16 [M][K]; Wt fp16 [N][K]. 128x128 tile, BK=64, 4 waves of 64x64.
// LDS: [row][8 chunks of 16B], chunk slot s holds global chunk s^(row&7)
// (XOR swizzle keeps global_load_lds legal AND ds_read_b128 2-way max).
template<bool QKV>
__global__ __launch_bounds__(256)
void gemm_f16(const _Float16* __restrict__ X,
              const _Float16* __restrict__ W0t, const _Float16* __restrict__ W1t,
              const _Float16* __restrict__ W2t,
              const float* __restrict__ B0, const float* __restrict__ B1,
              const float* __restrict__ B2,
              void* __restrict__ outv)
{
    __shared__ __align__(16) _Float16 As[128][64];   // 16 KB
    __shared__ __align__(16) _Float16 Bs[128][64];   // 16 KB

    const int tid = threadIdx.x;
    const int w = tid >> 6, lane = tid & 63;
    const int ln = lane & 15, quad = lane >> 4;
    const int bz = blockIdx.z;
    const _Float16* Wt = W0t; const float* bias = B0;
    if (QKV) { if (bz == 1) { Wt = W1t; bias = B1; } else if (bz == 2) { Wt = W2t; bias = B2; } }
    const int m0 = blockIdx.y * 128, n0 = blockIdx.x * 128;
    const int wm = w >> 1, wn = w & 1;
    const int row8 = lane >> 3, cch = lane & 7;
    const int gch = cch ^ row8;          // swizzled source chunk index

    f32x4 acc[4][4];
#pragma unroll
    for (int i = 0; i < 4; i++)
#pragma unroll
        for (int j = 0; j < 4; j++) acc[i][j] = (f32x4){0.f, 0.f, 0.f, 0.f};

    for (int k0 = 0; k0 < DIM; k0 += 64) {
        __syncthreads();
        // stage A & B: wave w covers rows [w*32, w*32+32) of each tile
#pragma unroll
        for (int j = 0; j < 4; j++) {
            const int r = w * 32 + j * 8;
            gload16(X  + (size_t)(m0 + r + row8) * DIM + k0 + gch * 8, &As[r][0]);
            gload16(Wt + (size_t)(n0 + r + row8) * DIM + k0 + gch * 8, &Bs[r][0]);
        }
        __syncthreads();

        half8 a[4][2], b[4][2];
#pragma unroll
        for (int mt = 0; mt < 4; mt++) {
            int m = wm * 64 + mt * 16 + ln;
#pragma unroll
            for (int ks = 0; ks < 2; ks++) {
                int s = (ks * 4 + quad) ^ (ln & 7);
                a[mt][ks] = *(const half8*)&As[m][s * 8];
            }
        }
#pragma unroll
        for (int nt = 0; nt < 4; nt++) {
            int n = wn * 64 + nt * 16 + ln;
#pragma unroll
            for (int ks = 0; ks < 2; ks++) {
                int s = (ks * 4 + quad) ^ (ln & 7);
                b[nt][ks] = *(const half8*)&Bs[n][s * 8];
            }
        }
#pragma unroll
        for (int ks = 0; ks < 2; ks++)
#pragma unroll
            for (int mt = 0; mt < 4; mt++)
#pragma unroll
                for (int nt = 0; nt < 4; nt++)
                    acc[mt][nt] = __builtin_amdgcn_mfma_f32_16x16x32_f16(
                        a[mt][ks], b[nt][ks], acc[mt][nt], 0, 0, 0);
    }

    // epilogue: C/D 16x16 layout col=ln, row=quad*4+reg
#pragma unroll
    for (int nt = 0; nt < 4; nt++) {
        int col = n0 + wn * 64 + nt * 16 + ln;
        float bv = bias[col];
        int head = col / HDIM, hd = col % HDIM;
#pragma unroll
        for (int mt = 0; mt < 4; mt++) {
#pragma unroll
            for (int r = 0; r < 4; r++) {
                int row = m0 + wm * 64 + mt * 16 + quad * 4 + r;
                float v = acc[mt][nt][r] + bv;
                if (QKV) {
                    ((_Float16*)outv)[(((size_t)bz * NHEADS + head) * S_LEN + row) * HDIM + hd]
                        = (_Float16)v;
                } else {
                    ((float*)outv)[(size_t)row * DIM + col] = v;
                }
            }
        }
    }
}

// ---------------- RoPE on fp16 q/k in place ----------------
__global__ __launch_bounds__(256)
void rope_kernel(_Float16* __restrict__ qh, _Float16* __restrict__ kh,
                 const float* __restrict__ fc, const float* __restrict__ fs)
{
    const int per_tensor = NHEADS * S_LEN * 32;
    int idx = blockIdx.x * 256 + threadIdx.x;
    if (idx >= 2 * per_tensor) return;
    _Float16* buf = (idx < per_tensor) ? qh : kh;
    int r  = idx % per_tensor;
    int head = r / (S_LEN * 32);
    int r2 = r % (S_LEN * 32);
    int s  = r2 >> 5;
    int jc = 16 + (r2 & 31);
    int pos = (jc < 32) ? (s >> 6) : (s & 63);
    float c  = fc[pos * NPAIR + jc];
    float sn = fs[pos * NPAIR + jc];
    size_t base = (((size_t)head * S_LEN) + s) * HDIM + 2 * jc;
    half2v xv = *(half2v*)&buf[base];
    float xr = (float)xv[0], xi = (float)xv[1];
    half2v y = { (_Float16)(xr * c - xi * sn), (_Float16)(xr * sn + xi * c) };
    *(half2v*)&buf[base] = y;
}

// ---------------- MFMA fp16 flash attention ----------------
__global__ __launch_bounds__(256)
void attn_mfma_kernel(const _Float16* __restrict__ qh, const _Float16* __restrict__ kh,
                      const _Float16* __restrict__ vh, _Float16* __restrict__ aoh)
{
    __shared__ __align__(16) _Float16 Ks[64][104];   // 13312 B
    __shared__ __align__(16) _Float16 Vt[96][72];    // 13824 B
    __shared__ __align__(16) _Float16 Ps[4][16][72]; //  9216 B

    const int tid  = threadIdx.x;
    const int wid  = tid >> 6;
    const int lane = tid & 63;
    const int ln   = lane & 15;
    const int quad = lane >> 4;
    const int h    = blockIdx.y;
    const int q0   = blockIdx.x * 64;
    const float scale_ = 0.10206207261596577f;  // 1/sqrt(96)

    half8 aq[3];
    {
        const _Float16* qrow = qh + (((size_t)h * S_LEN) + q0 + wid * 16 + ln) * HDIM;
#pragma unroll
        for (int kb3 = 0; kb3 < 3; kb3++) {
            half8 a = *(const half8*)&qrow[kb3 * 32 + quad * 8];
            half8 v;
#pragma unroll
            for (int i = 0; i < 8; i++) v[i] = (_Float16)((float)a[i] * scale_);
            aq[kb3] = v;
        }
    }

    f32x4 o[6];
#pragma unroll
    for (int dn = 0; dn < 6; dn++) o[dn] = (f32x4){0.f, 0.f, 0.f, 0.f};
    float m_[4] = {-INFINITY, -INFINITY, -INFINITY, -INFINITY};
    float l_[4] = {0.f, 0.f, 0.f, 0.f};

    const _Float16* kbase = kh + ((size_t)h * S_LEN) * HDIM;
    const unsigned short* vbase = (const unsigned short*)(vh + ((size_t)h * S_LEN) * HDIM);

    for (int kt = 0; kt < S_LEN / 64; ++kt) {
        const int j0 = kt * 64;
        __syncthreads();
        // stage K: 64 rows x 12 uint4-chunks (96 halves) per row
        for (int i = tid; i < 768; i += 256) {
            int row = i / 12, c8 = (i % 12) * 8;
            *(uint4*)&Ks[row][c8] = *(const uint4*)&kbase[(size_t)(j0 + row) * HDIM + c8];
        }
        // stage V transposed: [d][key] packed pairs
        for (int i = tid; i < 3072; i += 256) {
            int kp = i & 31, d = i >> 5;
            unsigned int a = vbase[(size_t)(j0 + 2 * kp) * HDIM + d];
            unsigned int b = vbase[(size_t)(j0 + 2 * kp + 1) * HDIM + d];
            *(unsigned int*)&Vt[d][2 * kp] = a | (b << 16);
        }
        __syncthreads();

        // QK^T
        f32x4 s[4];
#pragma unroll
        for (int nb = 0; nb < 4; nb++) {
            f32x4 acc = (f32x4){0.f, 0.f, 0.f, 0.f};
#pragma unroll
            for (int kb3 = 0; kb3 < 3; kb3++) {
                half8 bk = *(const half8*)&Ks[nb * 16 + ln][kb3 * 32 + quad * 8];
                acc = __builtin_amdgcn_mfma_f32_16x16x32_f16(aq[kb3], bk, acc, 0, 0, 0);
            }
            s[nb] = acc;
        }

        // online softmax
        float mx[4], al[4];
#pragma unroll
        for (int r = 0; r < 4; r++)
            mx[r] = fmaxf(fmaxf(s[0][r], s[1][r]), fmaxf(s[2][r], s[3][r]));
#pragma unroll
        for (int msk = 1; msk < 16; msk <<= 1)
#pragma unroll
            for (int r = 0; r < 4; r++) mx[r] = fmaxf(mx[r], __shfl_xor(mx[r], msk));
#pragma unroll
        for (int r = 0; r < 4; r++) {
            float mn = fmaxf(m_[r], mx[r]);
            al[r] = __expf(m_[r] - mn);
            m_[r] = mn;
        }
        float rs[4] = {0.f, 0.f, 0.f, 0.f};
#pragma unroll
        for (int nb = 0; nb < 4; nb++)
#pragma unroll
            for (int r = 0; r < 4; r++) {
                float p = __expf(s[nb][r] - m_[r]);
                s[nb][r] = p;
                rs[r] += p;
            }
#pragma unroll
        for (int msk = 1; msk < 16; msk <<= 1)
#pragma unroll
            for (int r = 0; r < 4; r++) rs[r] += __shfl_xor(rs[r], msk);
#pragma unroll
        for (int r = 0; r < 4; r++) l_[r] = l_[r] * al[r] + rs[r];

        // P -> wave-private LDS, A-layout, fp16 pair-packed
        {
            int rsel = (lane & 1) ? 2 : 0;
#pragma unroll
            for (int nb = 0; nb < 4; nb++) {
                int key = nb * 16 + ln;
                float pq[4];
#pragma unroll
                for (int r = 0; r < 4; r++) pq[r] = __shfl_xor(s[nb][r], 1);
                unsigned int wv[4];
#pragma unroll
                for (int r = 0; r < 4; r++)
                    wv[r] = (lane & 1) ? packh2(pq[r], s[nb][r]) : packh2(s[nb][r], pq[r]);
                int rbase = quad * 4 + rsel;
                *(unsigned int*)&Ps[wid][rbase][key & ~1]     = wv[rsel];
                *(unsigned int*)&Ps[wid][rbase + 1][key & ~1] = wv[rsel + 1];
            }
        }

#pragma unroll
        for (int dn = 0; dn < 6; dn++)
#pragma unroll
            for (int r = 0; r < 4; r++) o[dn][r] *= al[r];

        // PV
        half8 ap[2];
#pragma unroll
        for (int kb2 = 0; kb2 < 2; kb2++)
            ap[kb2] = *(const half8*)&Ps[wid][ln][kb2 * 32 + quad * 8];
#pragma unroll
        for (int dn = 0; dn < 6; dn++) {
#pragma unroll
            for (int kb2 = 0; kb2 < 2; kb2++) {
                half8 bv = *(const half8*)&Vt[dn * 16 + ln][kb2 * 32 + quad * 8];
                o[dn] = __builtin_amdgcn_mfma_f32_16x16x32_f16(ap[kb2], bv, o[dn], 0, 0, 0);
            }
        }
    }

    float inv[4];
#pragma unroll
    for (int r = 0; r < 4; r++) inv[r] = 1.f / l_[r];
#pragma unroll
    for (int dn = 0; dn < 6; dn++)
#pragma unroll
        for (int r = 0; r < 4; r++) {
            int row = q0 + wid * 16 + quad * 4 + r;
            aoh[(size_t)row * DIM + h * HDIM + dn * 16 + ln] = (_Float16)(o[dn][r] * inv[r]);
        }
}

extern "C" void kernel_launch(void* const* d_in, const int* in_sizes, int n_in,
                              void* d_out, int out_size, void* d_ws, size_t ws_size,
                              hipStream_t stream) {
    const float* x  = (const float*)d_in[0];
    const float* wq = (const float*)d_in[1];
    const float* bq = (const float*)d_in[2];
    const float* wk = (const float*)d_in[3];
    const float* bk = (const float*)d_in[4];
    const float* wv = (const float*)d_in[5];
    const float* bv = (const float*)d_in[6];
    const float* wo = (const float*)d_in[7];
    const float* bo = (const float*)d_in[8];
    const float* fc = (const float*)d_in[9];
    const float* fs = (const float*)d_in[10];
    float* out = (float*)d_out;

    const size_t per  = (size_t)NHEADS * S_LEN * HDIM;   // 4,718,592
    const size_t dim2 = (size_t)DIM * DIM;               // 2,359,296
    _Float16* hws  = (_Float16*)d_ws;
    _Float16* qkvh = hws;                 // q,k,v fp16: 3*per
    _Float16* qh   = qkvh;
    _Float16* kh   = qkvh + per;
    _Float16* vh   = qkvh + 2 * per;
    _Float16* xh   = hws + 3 * per;       // x fp16; later reused as ao fp16
    _Float16* wth  = hws + 4 * per;       // 4 transposed weights fp16

    // prep: x -> fp16; weights -> fp16 transposed [n][k]
    convert_f32_f16<<<(int)((S_LEN * DIM / 4 + 255) / 256), 256, 0, stream>>>(
        x, xh, S_LEN * DIM / 4);
    transpose_w<<<dim3(DIM / 64, DIM / 64, 4), 256, 0, stream>>>(wq, wk, wv, wo, wth);

    // fused QKV projection -> fp16 [z][head][s][hd]
    gemm_f16<true><<<dim3(DIM / 128, S_LEN / 128, 3), 256, 0, stream>>>(
        xh, wth, wth + dim2, wth + 2 * dim2, bq, bk, bv, qkvh);
    // RoPE on q,k
    rope_kernel<<<(2 * NHEADS * S_LEN * 32) / 256, 256, 0, stream>>>(qh, kh, fc, fs);
    // attention -> ao fp16 [s][dim] (reuses xh buffer)
    attn_mfma_kernel<<<dim3(S_LEN / 64, NHEADS), 256, 0, stream>>>(qh, kh, vh, xh);
    // output projection -> fp32 d_out
    gemm_f16<false><<<dim3(DIM / 128, S_LEN / 128, 1), 256, 0, stream>>>(
        xh, wth + 3 * dim2, nullptr, nullptr, bo, nullptr, nullptr, out);
}

// Round 5
// 361.056 us; speedup vs baseline: 8.6565x; 1.7164x over previous
//
#include <hip/hip_runtime.h>
#include <math.h>

#define S_LEN 3072
#define DIM 1536
#define NHEADS 16
#define HDIM 96
#define NPAIR 48

typedef __attribute__((ext_vector_type(8))) _Float16 half8;
typedef __attribute__((ext_vector_type(4))) _Float16 half4v;
typedef __attribute__((ext_vector_type(2))) _Float16 half2v;
typedef __attribute__((ext_vector_type(4))) float f32x4;

__device__ inline void gload16(const void* g, void* l) {
    __builtin_amdgcn_global_load_lds(
        (const __attribute__((address_space(1))) void*)g,
        (__attribute__((address_space(3))) void*)l, 16, 0, 0);
}

__device__ inline unsigned int packh2(float a, float b) {
    _Float16 ha = (_Float16)a, hb = (_Float16)b;
    unsigned short ua = *(unsigned short*)&ha;
    unsigned short ub = *(unsigned short*)&hb;
    return (unsigned int)ua | ((unsigned int)ub << 16);
}

// ---------------- prep: fp32 -> fp16 elementwise ----------------
__global__ __launch_bounds__(256)
void convert_f32_f16(const float* __restrict__ src, _Float16* __restrict__ dst, int n4)
{
    int i = blockIdx.x * 256 + threadIdx.x;
    if (i < n4) {
        float4 v = *(const float4*)&src[(size_t)i * 4];
        half4v h = { (_Float16)v.x, (_Float16)v.y, (_Float16)v.z, (_Float16)v.w };
        *(half4v*)&dst[(size_t)i * 4] = h;
    }
}

// ---------------- prep: W[k][n] fp32 -> Wt[n][k] fp16 (64x64 LDS tiles) ----------------
__global__ __launch_bounds__(256)
void transpose_w(const float* __restrict__ w0, const float* __restrict__ w1,
                 const float* __restrict__ w2, const float* __restrict__ w3,
                 _Float16* __restrict__ wt)
{
    __shared__ _Float16 t[64][68];
    const int z = blockIdx.z;
    const float* W = (z == 0) ? w0 : (z == 1) ? w1 : (z == 2) ? w2 : w3;
    _Float16* O = wt + (size_t)z * DIM * DIM;
    const int k0 = blockIdx.y * 64, n0 = blockIdx.x * 64;
    const int tid = threadIdx.x;
    const int r = tid >> 4, c4 = (tid & 15) * 4;
#pragma unroll
    for (int g = 0; g < 4; g++) {
        int kk = r + g * 16;
        float4 v = *(const float4*)&W[(size_t)(k0 + kk) * DIM + n0 + c4];
        t[c4 + 0][kk] = (_Float16)v.x; t[c4 + 1][kk] = (_Float16)v.y;
        t[c4 + 2][kk] = (_Float16)v.z; t[c4 + 3][kk] = (_Float16)v.w;
    }
    __syncthreads();
    const int nr = tid >> 2, ks = (tid & 3) * 16;
#pragma unroll
    for (int s = 0; s < 4; s++)
        *(ushort4*)&O[(size_t)(n0 + nr) * DIM + k0 + ks + s * 4] =
            *(ushort4*)&t[nr][ks + s * 4];
}

// ---------------- fp16 MFMA GEMM: out = Xh[M,K] @ Wt^T + bias ----------------
// QKV=true: q,k written [head][s][hd]; v written TRANSPOSED [head][hd][s].
template<bool QKV>
__global__ __launch_bounds__(256)
void gemm_f16(const _Float16* __restrict__ X,
              const _Float16* __restrict__ W0t, const _Float16* __restrict__ W1t,
              const _Float16* __restrict__ W2t,
              const float* __restrict__ B0, const float* __restrict__ B1,
              const float* __restrict__ B2,
              void* __restrict__ outv)
{
    __shared__ __align__(16) _Float16 As[128][64];   // 16 KB
    __shared__ __align__(16) _Float16 Bs[128][64];   // 16 KB

    const int tid = threadIdx.x;
    const int w = tid >> 6, lane = tid & 63;
    const int ln = lane & 15, quad = lane >> 4;
    const int bz = blockIdx.z;
    const _Float16* Wt = W0t; const float* bias = B0;
    if (QKV) { if (bz == 1) { Wt = W1t; bias = B1; } else if (bz == 2) { Wt = W2t; bias = B2; } }
    const int m0 = blockIdx.y * 128, n0 = blockIdx.x * 128;
    const int wm = w >> 1, wn = w & 1;
    const int row8 = lane >> 3, cch = lane & 7;
    const int gch = cch ^ row8;          // swizzled source chunk index

    f32x4 acc[4][4];
#pragma unroll
    for (int i = 0; i < 4; i++)
#pragma unroll
        for (int j = 0; j < 4; j++) acc[i][j] = (f32x4){0.f, 0.f, 0.f, 0.f};

    for (int k0 = 0; k0 < DIM; k0 += 64) {
        __syncthreads();
#pragma unroll
        for (int j = 0; j < 4; j++) {
            const int r = w * 32 + j * 8;
            gload16(X  + (size_t)(m0 + r + row8) * DIM + k0 + gch * 8, &As[r][0]);
            gload16(Wt + (size_t)(n0 + r + row8) * DIM + k0 + gch * 8, &Bs[r][0]);
        }
        __syncthreads();

        half8 a[4][2], b[4][2];
#pragma unroll
        for (int mt = 0; mt < 4; mt++) {
            int m = wm * 64 + mt * 16 + ln;
#pragma unroll
            for (int ks = 0; ks < 2; ks++) {
                int s = (ks * 4 + quad) ^ (ln & 7);
                a[mt][ks] = *(const half8*)&As[m][s * 8];
            }
        }
#pragma unroll
        for (int nt = 0; nt < 4; nt++) {
            int n = wn * 64 + nt * 16 + ln;
#pragma unroll
            for (int ks = 0; ks < 2; ks++) {
                int s = (ks * 4 + quad) ^ (ln & 7);
                b[nt][ks] = *(const half8*)&Bs[n][s * 8];
            }
        }
#pragma unroll
        for (int ks = 0; ks < 2; ks++)
#pragma unroll
            for (int mt = 0; mt < 4; mt++)
#pragma unroll
                for (int nt = 0; nt < 4; nt++)
                    acc[mt][nt] = __builtin_amdgcn_mfma_f32_16x16x32_f16(
                        a[mt][ks], b[nt][ks], acc[mt][nt], 0, 0, 0);
    }

    // epilogue: C/D 16x16 layout col=ln, row=quad*4+reg
#pragma unroll
    for (int nt = 0; nt < 4; nt++) {
        int col = n0 + wn * 64 + nt * 16 + ln;
        float bv = bias[col];
        int head = col / HDIM, hd = col % HDIM;
#pragma unroll
        for (int mt = 0; mt < 4; mt++) {
            int row0 = m0 + wm * 64 + mt * 16 + quad * 4;
            if (QKV && bz == 2) {
                // V^T [head][hd][s]: 4 consecutive s values -> packed 8B store
                half4v p;
#pragma unroll
                for (int r = 0; r < 4; r++) p[r] = (_Float16)(acc[mt][nt][r] + bv);
                *(half4v*)&((_Float16*)outv)[(((size_t)2 * NHEADS + head) * HDIM + hd) * S_LEN + row0] = p;
            } else {
#pragma unroll
                for (int r = 0; r < 4; r++) {
                    float v = acc[mt][nt][r] + bv;
                    if (QKV) {
                        ((_Float16*)outv)[(((size_t)bz * NHEADS + head) * S_LEN + row0 + r) * HDIM + hd]
                            = (_Float16)v;
                    } else {
                        ((float*)outv)[(size_t)(row0 + r) * DIM + col] = v;
                    }
                }
            }
        }
    }
}

// ---------------- RoPE on fp16 q/k in place ----------------
__global__ __launch_bounds__(256)
void rope_kernel(_Float16* __restrict__ qh, _Float16* __restrict__ kh,
                 const float* __restrict__ fc, const float* __restrict__ fs)
{
    const int per_tensor = NHEADS * S_LEN * 32;
    int idx = blockIdx.x * 256 + threadIdx.x;
    if (idx >= 2 * per_tensor) return;
    _Float16* buf = (idx < per_tensor) ? qh : kh;
    int r  = idx % per_tensor;
    int head = r / (S_LEN * 32);
    int r2 = r % (S_LEN * 32);
    int s  = r2 >> 5;
    int jc = 16 + (r2 & 31);
    int pos = (jc < 32) ? (s >> 6) : (s & 63);
    float c  = fc[pos * NPAIR + jc];
    float sn = fs[pos * NPAIR + jc];
    size_t base = (((size_t)head * S_LEN) + s) * HDIM + 2 * jc;
    half2v xv = *(half2v*)&buf[base];
    float xr = (float)xv[0], xi = (float)xv[1];
    half2v y = { (_Float16)(xr * c - xi * sn), (_Float16)(xr * sn + xi * c) };
    *(half2v*)&buf[base] = y;
}

// ---------------- MFMA fp16 flash attention, S^T formulation ----------------
// S^T = K*Q^T (A=K, B=Q) -> C/D cols = qrows -> per-lane softmax stats.
// P lands in the correct lane for the PV B-operand: pack + ds_write_b64, no shuffles.
// O^T += V^T * P (A=V^T from LDS, B=P); al/l are per-lane.
__global__ __launch_bounds__(256)
void attn_mfma_kernel(const _Float16* __restrict__ qh, const _Float16* __restrict__ kh,
                      const _Float16* __restrict__ vtg, _Float16* __restrict__ aoh)
{
    __shared__ __align__(16) _Float16 Ks[64][100];    // 12.5 KB, stride 200B (bank-clean)
    __shared__ __align__(16) _Float16 Vt[96][68];     // 12.75 KB, stride 136B
    __shared__ __align__(16) _Float16 Pl[4][16][72];  // 9 KB, wave-private

    const int tid  = threadIdx.x;
    const int wid  = tid >> 6;
    const int lane = tid & 63;
    const int ln   = lane & 15;
    const int quad = lane >> 4;
    const int h    = blockIdx.y;
    const int q0   = blockIdx.x * 64;
    const float scale_ = 0.10206207261596577f;  // 1/sqrt(96)

    // Q fragments (B-operand: lane(ln,quad) holds Q[qrow=ln][d=kb*32+quad*8+j])
    half8 aq[3];
    {
        const _Float16* qrow = qh + (((size_t)h * S_LEN) + q0 + wid * 16 + ln) * HDIM;
#pragma unroll
        for (int kb3 = 0; kb3 < 3; kb3++) {
            half8 a = *(const half8*)&qrow[kb3 * 32 + quad * 8];
            half8 v;
#pragma unroll
            for (int i = 0; i < 8; i++) v[i] = (_Float16)((float)a[i] * scale_);
            aq[kb3] = v;
        }
    }

    f32x4 o[6];  // O^T: o[dn][r] = O^T[dn*16+quad*4+r][qrow=ln]
#pragma unroll
    for (int dn = 0; dn < 6; dn++) o[dn] = (f32x4){0.f, 0.f, 0.f, 0.f};
    float m_ = -INFINITY, l_ = 0.f;   // per-lane (qrow = ln)

    const _Float16* kbase = kh + ((size_t)h * S_LEN) * HDIM;
    const _Float16* vbase = vtg + ((size_t)h * HDIM) * S_LEN;

    // staging index constants
    const int krow = tid / 4, kc8 = (tid & 3) * 3;        // K: 64 rows x 12 chunks; 3/thread
    const int vrow = tid / 2, vc8 = (tid & 1) * 4;        // V: 96 rows x 8 chunks via 2 grp... (see loop)

    for (int kt = 0; kt < S_LEN / 64; ++kt) {
        const int j0 = kt * 64;
        __syncthreads();
        // stage K tile: 64 keys x 96 d, uint4 chunks (3 per thread)
#pragma unroll
        for (int u = 0; u < 3; u++) {
            *(uint4*)&Ks[krow][(kc8 + u) * 8] =
                *(const uint4*)&kbase[(size_t)(j0 + krow) * HDIM + (kc8 + u) * 8];
        }
        // stage V^T tile: 96 d-rows x 64 keys, uint4 chunks (3 per thread)
        for (int i = tid; i < 768; i += 256) {
            int d = i >> 3, c = i & 7;
            *(uint4*)&Vt[d][c * 8] =
                *(const uint4*)&vbase[(size_t)d * S_LEN + j0 + c * 8];
        }
        __syncthreads();

        // S^T = K * Q^T : s[nb][r] = S^T[key=nb*16+quad*4+r][qrow=ln]
        f32x4 s[4];
#pragma unroll
        for (int nb = 0; nb < 4; nb++) {
            f32x4 acc = (f32x4){0.f, 0.f, 0.f, 0.f};
#pragma unroll
            for (int kb3 = 0; kb3 < 3; kb3++) {
                half8 ak = *(const half8*)&Ks[nb * 16 + ln][kb3 * 32 + quad * 8];
                acc = __builtin_amdgcn_mfma_f32_16x16x32_f16(ak, aq[kb3], acc, 0, 0, 0);
            }
            s[nb] = acc;
        }

        // per-lane online softmax over 16 regs, then reduce across quads (2 shfl each)
        float mx = s[0][0];
#pragma unroll
        for (int nb = 0; nb < 4; nb++)
#pragma unroll
            for (int r = 0; r < 4; r++) mx = fmaxf(mx, s[nb][r]);
        mx = fmaxf(mx, __shfl_xor(mx, 16));
        mx = fmaxf(mx, __shfl_xor(mx, 32));
        float mn = fmaxf(m_, mx);
        float al = __expf(m_ - mn);
        m_ = mn;
        float rs = 0.f;
#pragma unroll
        for (int nb = 0; nb < 4; nb++)
#pragma unroll
            for (int r = 0; r < 4; r++) {
                float p = __expf(s[nb][r] - mn);
                s[nb][r] = p;
                rs += p;
            }
        rs += __shfl_xor(rs, 16);
        rs += __shfl_xor(rs, 32);
        l_ = l_ * al + rs;

        // P -> wave-private LDS [qrow][key], values already in the right lane
#pragma unroll
        for (int nb = 0; nb < 4; nb++) {
            uint2 u;
            u.x = packh2(s[nb][0], s[nb][1]);
            u.y = packh2(s[nb][2], s[nb][3]);
            *(uint2*)&Pl[wid][ln][nb * 16 + quad * 4] = u;
        }

        // rescale O^T (al is per-lane)
#pragma unroll
        for (int dn = 0; dn < 6; dn++)
#pragma unroll
            for (int r = 0; r < 4; r++) o[dn][r] *= al;

        // O^T += V^T * P
        half8 ap[2];
#pragma unroll
        for (int c = 0; c < 2; c++)
            ap[c] = *(const half8*)&Pl[wid][ln][c * 32 + quad * 8];
#pragma unroll
        for (int dn = 0; dn < 6; dn++) {
#pragma unroll
            for (int c = 0; c < 2; c++) {
                half8 av = *(const half8*)&Vt[dn * 16 + ln][c * 32 + quad * 8];
                o[dn] = __builtin_amdgcn_mfma_f32_16x16x32_f16(av, ap[c], o[dn], 0, 0, 0);
            }
        }
    }

    const float invl = 1.f / l_;
    const size_t rowbase = (size_t)(q0 + wid * 16 + ln) * DIM + h * HDIM;
#pragma unroll
    for (int dn = 0; dn < 6; dn++) {
        half4v p;
#pragma unroll
        for (int r = 0; r < 4; r++) p[r] = (_Float16)(o[dn][r] * invl);
        *(half4v*)&aoh[rowbase + dn * 16 + quad * 4] = p;
    }
}

extern "C" void kernel_launch(void* const* d_in, const int* in_sizes, int n_in,
                              void* d_out, int out_size, void* d_ws, size_t ws_size,
                              hipStream_t stream) {
    const float* x  = (const float*)d_in[0];
    const float* wq = (const float*)d_in[1];
    const float* bq = (const float*)d_in[2];
    const float* wk = (const float*)d_in[3];
    const float* bk = (const float*)d_in[4];
    const float* wv = (const float*)d_in[5];
    const float* bv = (const float*)d_in[6];
    const float* wo = (const float*)d_in[7];
    const float* bo = (const float*)d_in[8];
    const float* fc = (const float*)d_in[9];
    const float* fs = (const float*)d_in[10];
    float* out = (float*)d_out;

    const size_t per  = (size_t)NHEADS * S_LEN * HDIM;   // 4,718,592
    const size_t dim2 = (size_t)DIM * DIM;               // 2,359,296
    _Float16* hws  = (_Float16*)d_ws;
    _Float16* qkvh = hws;                 // q,k fp16 [head][s][hd]; v fp16 [head][hd][s]
    _Float16* qh   = qkvh;
    _Float16* kh   = qkvh + per;
    _Float16* vth  = qkvh + 2 * per;
    _Float16* xh   = hws + 3 * per;       // x fp16; later reused as ao fp16
    _Float16* wth  = hws + 4 * per;       // 4 transposed weights fp16

    convert_f32_f16<<<(int)((S_LEN * DIM / 4 + 255) / 256), 256, 0, stream>>>(
        x, xh, S_LEN * DIM / 4);
    transpose_w<<<dim3(DIM / 64, DIM / 64, 4), 256, 0, stream>>>(wq, wk, wv, wo, wth);

    gemm_f16<true><<<dim3(DIM / 128, S_LEN / 128, 3), 256, 0, stream>>>(
        xh, wth, wth + dim2, wth + 2 * dim2, bq, bk, bv, qkvh);
    rope_kernel<<<(2 * NHEADS * S_LEN * 32) / 256, 256, 0, stream>>>(qh, kh, fc, fs);
    attn_mfma_kernel<<<dim3(S_LEN / 64, NHEADS), 256, 0, stream>>>(qh, kh, vth, xh);
    gemm_f16<false><<<dim3(DIM / 128, S_LEN / 128, 1), 256, 0, stream>>>(
        xh, wth + 3 * dim2, nullptr, nullptr, bo, nullptr, nullptr, out);
}